// Round 4
// baseline (328.515 us; speedup 1.0000x reference)
//
#include <hip/hip_runtime.h>
#include <math.h>

// HW exp2 (v_exp_f32) when available.
#if defined(__has_builtin)
#  if __has_builtin(__builtin_amdgcn_exp2f)
#    define EXP2F(x) __builtin_amdgcn_exp2f(x)
#  endif
#endif
#ifndef EXP2F
#  define EXP2F(x) __expf(0.69314718055994530942f * (x))
#endif

// Full-rate-VALU exp2: magic-constant round-to-nearest, deg-3 Taylor on
// f in [-0.5,0.5] (rel err <= 6e-4), exponent rebuilt via (y_int<<23)+p_int.
__device__ __forceinline__ float fast_exp2(float x) {
  const float M = 12582912.0f;             // 1.5 * 2^23
  const float y = x + M;                   // RNE(x) encoded in mantissa
  const float n = y - M;
  const float f = x - n;                   // [-0.5, 0.5]
  float p = fmaf(f, 0.055504109f, 0.24022651f);
  p = fmaf(f, p, 0.69314718f);
  p = fmaf(f, p, 1.0f);                    // 2^f
  const int r = (__float_as_int(y) << 23) + __float_as_int(p);
  return __int_as_float(r);
}

// R7: accounting from R5/R6 closes the books: total VALU-busy work = 38 us
// (R5: 5.9% x 656), baseline = 38/0.31 = 122 ~ 124 us measured. The whole
// cost is machine-wide VALU issue at ~31%: half-idle CUs (tail kernels) +
// ramps/drains. cg::grid.sync costs ~170us/sync (R5) so instead: ONE
// cooperative kernel, every layer decomposed into ~1024 tiles (full machine),
// fine-grained per-row-tile flags (device-scope release-add / acquire-spin)
// so blocks flow into the next layer as soon as their inputs are ready.
// Cooperative launch guarantees co-residency => spin is deadlock-free
// (each block finishes all its L0 tiles before its first spin).
// Inner tile math identical to the validated R4 kernel (absmax 0.0).

__device__ __forceinline__ float c2_of(const float* __restrict__ tp, float tf) {
  const float ta  = tp[0];
  const float tau = tf + (ta >= 0.0f ? ta : 0.05f * ta);
  return tau * 1.44269504088896340736f;    // tau * log2(e)
}

__device__ __forceinline__ void wait_flag(const unsigned int* __restrict__ f,
                                          unsigned int need) {
  while (__hip_atomic_load(f, __ATOMIC_ACQUIRE, __HIP_MEMORY_SCOPE_AGENT) < need)
    __builtin_amdgcn_s_sleep(2);
}

__device__ __forceinline__ void signal_flag(unsigned int* __restrict__ f) {
  __threadfence();                         // agent release (L2 writeback)
  __hip_atomic_fetch_add(f, 1u, __ATOMIC_RELEASE, __HIP_MEMORY_SCOPE_AGENT);
}

// ---- tile staging: BB rows x IN floats -> LDS (FIRST: h = concat(x,1-x)) ----
template <int IN, int BB, bool FIRST>
__device__ __forceinline__ void stage_tile(const float* __restrict__ hin,
                                           int b0, float4* __restrict__ lds_h) {
  constexpr int IN4 = IN / 4;
  const int tid = threadIdx.x;
  const float4* __restrict__ Hv = (const float4*)hin;
  if (FIRST) {
    constexpr int HALF4 = IN / 8;
    for (int idx = tid; idx < BB * HALF4; idx += 256) {
      const int r = idx / HALF4;
      const int k = idx - r * HALF4;
      const float4 v = Hv[(b0 + r) * HALF4 + k];
      lds_h[r * IN4 + k] = v;
      lds_h[r * IN4 + HALF4 + k] =
          make_float4(1.0f - v.x, 1.0f - v.y, 1.0f - v.z, 1.0f - v.w);
    }
  } else {
    for (int idx = tid; idx < BB * IN4; idx += 256) {
      const int r = idx / IN4;
      const int k = idx - r * IN4;
      lds_h[r * IN4 + k] = Hv[(b0 + r) * IN4 + k];
    }
  }
}

// ---- tile compute: validated R4 inner loop (hybrid exp, W prefetch) ----
template <int IN, int OUT, int BB>
__device__ __forceinline__ void compute_tile(const float* __restrict__ W,
                                             float c2,
                                             float* __restrict__ hout,
                                             int b0, int o0,
                                             const float4* __restrict__ lds_h) {
  constexpr int OBB = 2;
  constexpr int NIT = IN / 64;
  constexpr int IN4 = IN / 4;

  const int lane = threadIdx.x & 63;
  const int il   = lane & 15;

  const float4* __restrict__ Wv = (const float4*)W;

  float s[BB][OBB], t[BB][OBB];
#pragma unroll
  for (int r = 0; r < BB; ++r)
#pragma unroll
    for (int c = 0; c < OBB; ++c) { s[r][c] = 0.0f; t[r][c] = 0.0f; }

  const float4* wp0 = Wv + (size_t)(o0 + 0) * IN4 + il;
  const float4* wp1 = Wv + (size_t)(o0 + 1) * IN4 + il;
  float4 wcur0 = wp0[0];
  float4 wcur1 = wp1[0];

#pragma unroll 2
  for (int ic = 0; ic < NIT; ++ic) {
    const int icn = (ic + 1 < NIT) ? (ic + 1) : (NIT - 1);
    const float4 wnxt0 = wp0[icn * 16];
    const float4 wnxt1 = wp1[icn * 16];

    float hc[BB][4];
#pragma unroll
    for (int r = 0; r < BB; ++r) {
      const float4 v = lds_h[r * IN4 + ic * 16 + il];
      hc[r][0] = v.x; hc[r][1] = v.y; hc[r][2] = v.z; hc[r][3] = v.w;
    }

    float cw[OBB][4];
    {
      const float wj0[4] = {wcur0.x, wcur0.y, wcur0.z, wcur0.w};
      const float wj1[4] = {wcur1.x, wcur1.y, wcur1.z, wcur1.w};
#pragma unroll
      for (int j = 0; j < 4; ++j) {
        float m  = fminf(fmaxf(wj0[j], 0.0f), 1.0f);      // med3 clamp
        cw[0][j] = c2 * fmaf(0.1f, wj0[j] - m, m);        // leaky outside
        m        = fminf(fmaxf(wj1[j], 0.0f), 1.0f);
        cw[1][j] = c2 * fmaf(0.1f, wj1[j] - m, m);
      }
    }

#pragma unroll
    for (int r = 0; r < BB; ++r)
#pragma unroll
      for (int c = 0; c < OBB; ++c)
#pragma unroll
        for (int j = 0; j < 4; ++j) {
          const float arg = cw[c][j] * hc[r][j];
          // Hybrid: even j on the trans pipe, odd j full-rate.
          const float e = (j & 1) ? fast_exp2(arg) : EXP2F(arg);
          s[r][c] += e;
          t[r][c]  = fmaf(arg, e, t[r][c]);
        }

    wcur0 = wnxt0;
    wcur1 = wnxt1;
  }

#pragma unroll
  for (int m = 1; m < 16; m <<= 1)
#pragma unroll
    for (int r = 0; r < BB; ++r)
#pragma unroll
      for (int c = 0; c < OBB; ++c) {
        s[r][c] += __shfl_xor(s[r][c], m, 64);
        t[r][c] += __shfl_xor(t[r][c], m, 64);
      }

  if (il == 0) {
    const float inv_c2 = 1.0f / c2;
#pragma unroll
    for (int r = 0; r < BB; ++r)
#pragma unroll
      for (int c = 0; c < OBB; ++c) {
        const float out = t[r][c] / s[r][c] * inv_c2;  // sum(z e)/sum(e)
        hout[(b0 + r) * OUT + (o0 + c)] = 1.0f - out;
      }
  }
}

// ---- flag init (workspace is poisoned each iteration) ----
__global__ void zero_flags(unsigned int* __restrict__ f) {
  f[threadIdx.x] = 0u;                     // 256 slots, 224 used
}

// ---- the fused persistent kernel ----
// Tiles per phase: L0 32ot x 32rt(BB=4) = 1024; L1 16 x 64(BB=2) = 1024;
// L2 8 x 128(BB=1) = 1024; L3 4 x 128 = 512.
// flag1[32] complete at 32; flag2[64] at 16; flag3[128] at 8.
__launch_bounds__(256, 4)
__global__ void fused_all(const float* __restrict__ x,
                          const float* __restrict__ W0, const float* __restrict__ tau0,
                          const float* __restrict__ W1, const float* __restrict__ tau1,
                          const float* __restrict__ W2, const float* __restrict__ tau2,
                          const float* __restrict__ W3, const float* __restrict__ tau3,
                          float* __restrict__ h1, float* __restrict__ h2,
                          float* __restrict__ h3, float* __restrict__ out,
                          unsigned int* __restrict__ flags,
                          float tf0, float tf1, float tf2, float tf3) {
  __shared__ float4 lds_h[1024];           // 16KB, reused by every phase

  const int tid = threadIdx.x;
  const int wid = tid >> 6;
  const int og  = (tid >> 4) & 3;
  const int ob  = wid * 8 + og * 2;        // this thread's out-offset in a tile
  const int nb  = gridDim.x;

  unsigned int* flag1 = flags;             // 32
  unsigned int* flag2 = flags + 32;        // 64
  unsigned int* flag3 = flags + 96;        // 128

  const float c2_0 = c2_of(tau0, tf0);
  const float c2_1 = c2_of(tau1, tf1);
  const float c2_2 = c2_of(tau2, tf2);
  const float c2_3 = c2_of(tau3, tf3);

  // ---- phase 0: x -> h1 (no dependencies) ----
  for (int t = blockIdx.x; t < 1024; t += nb) {
    const int ot = t & 31, bt = t >> 5, b0 = bt * 4;
    __syncthreads();
    stage_tile<1024, 4, true>(x, b0, lds_h);
    __syncthreads();
    compute_tile<1024, 1024, 4>(W0, c2_0, h1, b0, ot * 32 + ob, lds_h);
    __syncthreads();
    if (tid == 0) signal_flag(&flag1[bt]);
  }

  // ---- phase 1: h1 -> h2 ----
  for (int t = blockIdx.x; t < 1024; t += nb) {
    const int ot = t & 15, rt = t >> 4, b0 = rt * 2;
    if (tid == 0) wait_flag(&flag1[rt >> 1], 32u);
    __syncthreads();
    stage_tile<1024, 2, false>(h1, b0, lds_h);
    __syncthreads();
    compute_tile<1024, 512, 2>(W1, c2_1, h2, b0, ot * 32 + ob, lds_h);
    __syncthreads();
    if (tid == 0) signal_flag(&flag2[rt]);
  }

  // ---- phase 2: h2 -> h3 ----
  for (int t = blockIdx.x; t < 1024; t += nb) {
    const int ot = t & 7, r = t >> 3;
    if (tid == 0) wait_flag(&flag2[r >> 1], 16u);
    __syncthreads();
    stage_tile<512, 1, false>(h2, r, lds_h);
    __syncthreads();
    compute_tile<512, 256, 1>(W2, c2_2, h3, r, ot * 32 + ob, lds_h);
    __syncthreads();
    if (tid == 0) signal_flag(&flag3[r]);
  }

  // ---- phase 3: h3 -> out ----
  for (int t = blockIdx.x; t < 512; t += nb) {
    const int ot = t & 3, r = t >> 2;
    if (tid == 0) wait_flag(&flag3[r], 8u);
    __syncthreads();
    stage_tile<256, 1, false>(h3, r, lds_h);
    __syncthreads();
    compute_tile<256, 128, 1>(W3, c2_3, out, r, ot * 32 + ob, lds_h);
    __syncthreads();
  }
}

// ---- fallback: the validated 124-us 4-kernel path ----
template <int IN, int OUT, int BB, bool FIRST>
__launch_bounds__(256, 4)
__global__ void or_layer(const float* __restrict__ hin,
                         const float* __restrict__ W,
                         const float* __restrict__ tau_ptr,
                         float* __restrict__ hout,
                         float tau_floor) {
  constexpr int nOT = OUT / 32;
  __shared__ float4 lds_h[(BB * IN) / 4];
  const int tid = threadIdx.x;
  const int wid = tid >> 6;
  const int og  = (tid >> 4) & 3;
  const int ot  = blockIdx.x % nOT;
  const int bt  = blockIdx.x / nOT;
  const int b0  = bt * BB;
  const float c2 = c2_of(tau_ptr, tau_floor);
  stage_tile<IN, BB, FIRST>(hin, b0, lds_h);
  __syncthreads();
  compute_tile<IN, OUT, BB>(W, c2, hout, b0, ot * 32 + wid * 8 + og * 2, lds_h);
}

extern "C" void kernel_launch(void* const* d_in, const int* in_sizes, int n_in,
                              void* d_out, int out_size, void* d_ws, size_t ws_size,
                              hipStream_t stream) {
  // setup_inputs() dict order: x, W0, tau0, W1, tau1, W2, tau2, W3, tau3
  const float* x    = (const float*)d_in[0];
  const float* W0   = (const float*)d_in[1];
  const float* tau0 = (const float*)d_in[2];
  const float* W1   = (const float*)d_in[3];
  const float* tau1 = (const float*)d_in[4];
  const float* W2   = (const float*)d_in[5];
  const float* tau2 = (const float*)d_in[6];
  const float* W3   = (const float*)d_in[7];
  const float* tau3 = (const float*)d_in[8];

  float* h1 = (float*)d_ws;                // 128*1024
  float* h2 = h1 + 128 * 1024;             // 128*512
  float* h3 = h2 + 128 * 512;              // 128*256
  unsigned int* flags = (unsigned int*)(h3 + 128 * 256);  // 256 uints
  float* out = (float*)d_out;              // 128*128

  const double LOGR = 2.9444389791664403;  // log(0.95) - log(0.05) = log(19)
  float tf1024 = (float)(log(1023.0) + LOGR);
  float tf512  = (float)(log(511.0)  + LOGR);
  float tf256  = (float)(log(255.0)  + LOGR);

  static int nblk = 0;
  if (nblk == 0) {
    int per_cu = 0;
    if (hipOccupancyMaxActiveBlocksPerMultiprocessor(&per_cu, fused_all, 256, 0)
            != hipSuccess || per_cu <= 0)
      per_cu = 1;
    if (per_cu > 4) per_cu = 4;
    nblk = per_cu * 256;
    if (nblk > 1024) nblk = 1024;
  }

  zero_flags<<<1, 256, 0, stream>>>(flags);

  void* args[] = {&x,  &W0, &tau0, &W1, &tau1, &W2, &tau2, &W3, &tau3,
                  &h1, &h2, &h3,   &out, &flags,
                  &tf1024, &tf1024, &tf512, &tf256};
  hipError_t err = hipLaunchCooperativeKernel(
      fused_all, dim3(nblk), dim3(256), args, 0, stream);

  if (err != hipSuccess) {
    // Validated R4 path.
    or_layer<1024, 1024, 4, true ><<<1024, 256, 0, stream>>>(x,  W0, tau0, h1,  tf1024);
    or_layer<1024,  512, 2, false><<<1024, 256, 0, stream>>>(h1, W1, tau1, h2,  tf1024);
    or_layer< 512,  256, 1, false><<<1024, 256, 0, stream>>>(h2, W2, tau2, h3,  tf512);
    or_layer< 256,  128, 1, false><<< 512, 256, 0, stream>>>(h3, W3, tau3, out, tf256);
  }
}

// Round 5
// 125.180 us; speedup vs baseline: 2.6243x; 2.6243x over previous
//
#include <hip/hip_runtime.h>
#include <math.h>

// HW exp2 (v_exp_f32) when available.
#if defined(__has_builtin)
#  if __has_builtin(__builtin_amdgcn_exp2f)
#    define EXP2F(x) __builtin_amdgcn_exp2f(x)
#  endif
#endif
#ifndef EXP2F
#  define EXP2F(x) __expf(0.69314718055994530942f * (x))
#endif

// R8: accounting from R4-R7 shows a fixed ~80 us/iter outside our control
// (256MB workspace re-poison fills @6.6TB/s = 40us each + launch overhead);
// controllable kernel time ~44 us, VALU-issue-bound (per-ic 576 VALU cyc vs
// 256 trans cyc). This round: pack the inner loop with CDNA packed-FP32
// VOP3P ops (v_pk_{mul,add,fma}_f32 = 2 f32 lanes per issue slot; the
// compiler never auto-emits them) via inline asm. j0,j1 -> trans pipe,
// j2,j3 -> fully packed fast_exp2. Binding VALU/ic 576 -> ~370 cyc,
// pipes near-balanced. Structure/grids identical to the validated
// 123.8-us 4-kernel path.

typedef float f32x2 __attribute__((ext_vector_type(2)));

__device__ __forceinline__ f32x2 pk_mul(f32x2 a, f32x2 b) {
  f32x2 d;
  asm("v_pk_mul_f32 %0, %1, %2" : "=v"(d) : "v"(a), "v"(b));
  return d;
}
__device__ __forceinline__ f32x2 pk_add(f32x2 a, f32x2 b) {
  f32x2 d;
  asm("v_pk_add_f32 %0, %1, %2" : "=v"(d) : "v"(a), "v"(b));
  return d;
}
__device__ __forceinline__ f32x2 pk_fma(f32x2 a, f32x2 b, f32x2 c) {
  f32x2 d;
  asm("v_pk_fma_f32 %0, %1, %2, %3" : "=v"(d) : "v"(a), "v"(b), "v"(c));
  return d;
}

union q4 { float4 f4; f32x2 p2[2]; };

// One layer of the OR-gate net:
//   aw = leaky_clamp(W, 0, 1, 0.1); z = h*aw
//   out[b,o] = sum_i z * softmax_i(tau*z); hout = 1 - out
// Folding: arg = c2*z, c2 = tau*log2(e); sum z*e = (sum arg*e)/c2.
// cw folding: c2*aw = c2*(m + 0.1*(w-m)) = w*(0.1c2) + m*(0.9c2).
template <int IN, int OUT, int BB, bool FIRST>
__launch_bounds__(256, 4)
__global__ void or_layer(const float* __restrict__ hin,
                         const float* __restrict__ W,
                         const float* __restrict__ tau_ptr,
                         float* __restrict__ hout,
                         float tau_floor) {
  constexpr int OBB = 2;                 // outputs per 16-lane group
  constexpr int NIT = IN / 64;           // 16 lanes x float4 per iter
  constexpr int nOT = OUT / 32;          // 4 waves x 8 outputs per block
  constexpr int IN4 = IN / 4;            // row length in float4

  __shared__ float4 lds_h[BB * IN4];

  const int tid  = threadIdx.x;
  const int lane = tid & 63;
  const int wid  = tid >> 6;
  const int il   = lane & 15;            // i-lane within group
  const int og   = lane >> 4;            // o-group 0..3

  const int ot = blockIdx.x % nOT;
  const int bt = blockIdx.x / nOT;
  const int b0 = bt * BB;
  const int o0 = ot * 32 + wid * 8 + og * OBB;

  const float ta  = tau_ptr[0];
  const float tau = tau_floor + (ta >= 0.0f ? ta : 0.05f * ta);
  const float c2  = tau * 1.44269504088896340736f;  // tau * log2(e)
  const float c01 = 0.1f * c2;           // folded leaky slope
  const float c09 = 0.9f * c2;

  // Packed constants (held in VGPR pairs for the asm ops).
  const f32x2 MM   = {12582912.0f, 12582912.0f};    // 1.5 * 2^23
  const f32x2 nMM  = {-12582912.0f, -12582912.0f};
  const f32x2 nONE = {-1.0f, -1.0f};
  const f32x2 K3   = {0.055504109f, 0.055504109f};
  const f32x2 K2   = {0.24022651f, 0.24022651f};
  const f32x2 K1   = {0.69314718f, 0.69314718f};
  const f32x2 ONE1 = {1.0f, 1.0f};

  const float4* __restrict__ Wv = (const float4*)W;
  const float4* __restrict__ Hv = (const float4*)hin;

  if (FIRST) {
    // hin is x: (128, IN/2); h = concat(x, 1-x).
    constexpr int HALF4 = IN / 8;
    for (int idx = tid; idx < BB * HALF4; idx += 256) {
      const int r = idx / HALF4;
      const int k = idx - r * HALF4;
      const float4 v = Hv[(b0 + r) * HALF4 + k];
      lds_h[r * IN4 + k] = v;
      lds_h[r * IN4 + HALF4 + k] =
          make_float4(1.0f - v.x, 1.0f - v.y, 1.0f - v.z, 1.0f - v.w);
    }
  } else {
    for (int idx = tid; idx < BB * IN4; idx += 256) {
      const int r = idx / IN4;
      const int k = idx - r * IN4;
      lds_h[r * IN4 + k] = Hv[(b0 + r) * IN4 + k];
    }
  }
  __syncthreads();

  float s[BB][OBB], t[BB][OBB];
#pragma unroll
  for (int r = 0; r < BB; ++r)
#pragma unroll
    for (int c = 0; c < OBB; ++c) { s[r][c] = 0.0f; t[r][c] = 0.0f; }

  // W stream: software pipeline, prefetch distance = 1 ic iteration.
  const float4* wp0 = Wv + (size_t)(o0 + 0) * IN4 + il;
  const float4* wp1 = Wv + (size_t)(o0 + 1) * IN4 + il;
  float4 wcur0 = wp0[0];
  float4 wcur1 = wp1[0];

#pragma unroll 2
  for (int ic = 0; ic < NIT; ++ic) {
    const int icn = (ic + 1 < NIT) ? (ic + 1) : (NIT - 1);
    const float4 wnxt0 = wp0[icn * 16];
    const float4 wnxt1 = wp1[icn * 16];

    // h tile from LDS as packed pairs (subregisters of the b128 load).
    f32x2 h01[BB], h23[BB];
#pragma unroll
    for (int r = 0; r < BB; ++r) {
      q4 u; u.f4 = lds_h[r * IN4 + ic * 16 + il];
      h01[r] = u.p2[0];
      h23[r] = u.p2[1];
    }

    // cw = c2 * leaky_clamp(w): med3 clamp + folded-constant fma, packed
    // pairs built once per ic, reused across BB rows.
    f32x2 cw01[OBB], cw23[OBB];
    {
      const float4 wq[OBB] = {wcur0, wcur1};
#pragma unroll
      for (int c = 0; c < OBB; ++c) {
        const float wj[4] = {wq[c].x, wq[c].y, wq[c].z, wq[c].w};
        float cs[4];
#pragma unroll
        for (int j = 0; j < 4; ++j) {
          const float m = fminf(fmaxf(wj[j], 0.0f), 1.0f);   // v_med3
          cs[j] = fmaf(wj[j], c01, m * c09);
        }
        cw01[c].x = cs[0]; cw01[c].y = cs[1];
        cw23[c].x = cs[2]; cw23[c].y = cs[3];
      }
    }

#pragma unroll
    for (int r = 0; r < BB; ++r)
#pragma unroll
      for (int c = 0; c < OBB; ++c) {
        // ---- trans pair (j0,j1): packed arg, v_exp_f32 per element ----
        const f32x2 a01 = pk_mul(cw01[c], h01[r]);
        const float e0 = EXP2F(a01.x);
        const float e1 = EXP2F(a01.y);
        // ---- fast pair (j2,j3): fully packed fast_exp2 ----
        const f32x2 a23 = pk_mul(cw23[c], h23[r]);
        const f32x2 y  = pk_add(a23, MM);       // RNE(x) in mantissa
        const f32x2 n  = pk_add(y, nMM);
        const f32x2 f  = pk_fma(n, nONE, a23);  // f = x - n, [-0.5,0.5]
        f32x2 p        = pk_fma(f, K3, K2);
        p              = pk_fma(f, p, K1);
        p              = pk_fma(f, p, ONE1);    // 2^f
        const float e2 = __int_as_float((__float_as_int(y.x) << 23) +
                                        __float_as_int(p.x));
        const float e3 = __int_as_float((__float_as_int(y.y) << 23) +
                                        __float_as_int(p.y));
        // ---- accumulate ----
        s[r][c] += e0; t[r][c] = fmaf(a01.x, e0, t[r][c]);
        s[r][c] += e1; t[r][c] = fmaf(a01.y, e1, t[r][c]);
        s[r][c] += e2; t[r][c] = fmaf(a23.x, e2, t[r][c]);
        s[r][c] += e3; t[r][c] = fmaf(a23.y, e3, t[r][c]);
      }

    wcur0 = wnxt0;
    wcur1 = wnxt1;
  }

  // Reduce partials across the 16 i-lanes of each group.
#pragma unroll
  for (int m = 1; m < 16; m <<= 1)
#pragma unroll
    for (int r = 0; r < BB; ++r)
#pragma unroll
      for (int c = 0; c < OBB; ++c) {
        s[r][c] += __shfl_xor(s[r][c], m, 64);
        t[r][c] += __shfl_xor(t[r][c], m, 64);
      }

  if (il == 0) {
    const float inv_c2 = 1.0f / c2;
#pragma unroll
    for (int r = 0; r < BB; ++r)
#pragma unroll
      for (int c = 0; c < OBB; ++c) {
        const float out = t[r][c] / s[r][c] * inv_c2;  // sum(z e)/sum(e)
        hout[(b0 + r) * OUT + (o0 + c)] = 1.0f - out;
      }
  }
}

extern "C" void kernel_launch(void* const* d_in, const int* in_sizes, int n_in,
                              void* d_out, int out_size, void* d_ws, size_t ws_size,
                              hipStream_t stream) {
  // setup_inputs() dict order: x, W0, tau0, W1, tau1, W2, tau2, W3, tau3
  const float* x    = (const float*)d_in[0];
  const float* W0   = (const float*)d_in[1];
  const float* tau0 = (const float*)d_in[2];
  const float* W1   = (const float*)d_in[3];
  const float* tau1 = (const float*)d_in[4];
  const float* W2   = (const float*)d_in[5];
  const float* tau2 = (const float*)d_in[6];
  const float* W3   = (const float*)d_in[7];
  const float* tau3 = (const float*)d_in[8];

  float* h1  = (float*)d_ws;        // 128*1024 floats
  float* h2  = h1 + 128 * 1024;     // 128*512
  float* h3  = h2 + 128 * 512;      // 128*256
  float* out = (float*)d_out;       // 128*128

  const double LOGR = 2.9444389791664403;  // log(0.95) - log(0.05) = log(19)
  const float tf1024 = (float)(log(1023.0) + LOGR);
  const float tf512  = (float)(log(511.0)  + LOGR);
  const float tf256  = (float)(log(255.0)  + LOGR);

  // Grid = (OUT/32) * (128/BB) — the validated 123.8-us configuration.
  or_layer<1024, 1024, 4, true ><<<1024, 256, 0, stream>>>(x,  W0, tau0, h1,  tf1024);
  or_layer<1024,  512, 2, false><<<1024, 256, 0, stream>>>(h1, W1, tau1, h2,  tf1024);
  or_layer< 512,  256, 1, false><<<1024, 256, 0, stream>>>(h2, W2, tau2, h3,  tf512);
  or_layer< 256,  128, 1, false><<< 512, 256, 0, stream>>>(h3, W3, tau3, out, tf256);
}

// Round 6
// 118.106 us; speedup vs baseline: 2.7815x; 1.0599x over previous
//
#include <hip/hip_runtime.h>
#include <math.h>

// HW exp2 (v_exp_f32) when available.
#if defined(__has_builtin)
#  if __has_builtin(__builtin_amdgcn_exp2f)
#    define EXP2F(x) __builtin_amdgcn_exp2f(x)
#  endif
#endif
#ifndef EXP2F
#  define EXP2F(x) __expf(0.69314718055994530942f * (x))
#endif

// R9: R8's null proved gfx950 has no packed-FP32 throughput headroom (157.3
// TF peak == scalar-FMA full rate), so the VALU op count barely moved.
// Remaining un-falsified inner-loop variable: the exp pipe mix. The 2-trans/
// 2-fast hybrid was designed for a 16-lanes/cyc/CU trans rate (gfx90a
// SIMD-16 assumption); CDNA4 SIMDs are 32-wide, so quarter-rate v_exp_f32
// would be 8 cyc/wave64 = 32 lanes/cyc/CU -> the trans pipe can absorb ALL
// 222M exps in ~11 us, and every fast_exp2 wastes ~7 full-rate VALU inst
// (the binding pipe) to spare an idle one. This round: all-trans exp
// (fast_exp2 deleted), everything else bit-identical to the validated R4
// structure. Per-quad binding cost 28 VALU inst -> 14 VALU + 4 trans.
// A/B readout also pins the true trans rate for the session journal.

// One layer of the OR-gate net:
//   aw = leaky_clamp(W, 0, 1, 0.1); z = h*aw
//   out[b,o] = sum_i z * softmax_i(tau*z); hout = 1 - out
// Folding: arg = c2*z, c2 = tau*log2(e); sum z*e = (sum arg*e)/c2.
// cw folding: c2*aw = w*(0.1*c2) + med3(w,0,1)*(0.9*c2).
template <int IN, int OUT, int BB, bool FIRST>
__launch_bounds__(256, 4)
__global__ void or_layer(const float* __restrict__ hin,
                         const float* __restrict__ W,
                         const float* __restrict__ tau_ptr,
                         float* __restrict__ hout,
                         float tau_floor) {
  constexpr int OBB = 2;                 // outputs per 16-lane group
  constexpr int NIT = IN / 64;           // 16 lanes x float4 per iter
  constexpr int nOT = OUT / 32;          // 4 waves x 8 outputs per block
  constexpr int IN4 = IN / 4;            // row length in float4

  __shared__ float4 lds_h[BB * IN4];

  const int tid  = threadIdx.x;
  const int lane = tid & 63;
  const int wid  = tid >> 6;
  const int il   = lane & 15;            // i-lane within group
  const int og   = lane >> 4;            // o-group 0..3

  const int ot = blockIdx.x % nOT;
  const int bt = blockIdx.x / nOT;
  const int b0 = bt * BB;
  const int o0 = ot * 32 + wid * 8 + og * OBB;

  const float ta  = tau_ptr[0];
  const float tau = tau_floor + (ta >= 0.0f ? ta : 0.05f * ta);
  const float c2  = tau * 1.44269504088896340736f;  // tau * log2(e)
  const float c01 = 0.1f * c2;           // folded leaky slope
  const float c09 = 0.9f * c2;

  const float4* __restrict__ Wv = (const float4*)W;
  const float4* __restrict__ Hv = (const float4*)hin;

  if (FIRST) {
    // hin is x: (128, IN/2); h = concat(x, 1-x).
    constexpr int HALF4 = IN / 8;
    for (int idx = tid; idx < BB * HALF4; idx += 256) {
      const int r = idx / HALF4;
      const int k = idx - r * HALF4;
      const float4 v = Hv[(b0 + r) * HALF4 + k];
      lds_h[r * IN4 + k] = v;
      lds_h[r * IN4 + HALF4 + k] =
          make_float4(1.0f - v.x, 1.0f - v.y, 1.0f - v.z, 1.0f - v.w);
    }
  } else {
    for (int idx = tid; idx < BB * IN4; idx += 256) {
      const int r = idx / IN4;
      const int k = idx - r * IN4;
      lds_h[r * IN4 + k] = Hv[(b0 + r) * IN4 + k];
    }
  }
  __syncthreads();

  float s[BB][OBB], t[BB][OBB];
#pragma unroll
  for (int r = 0; r < BB; ++r)
#pragma unroll
    for (int c = 0; c < OBB; ++c) { s[r][c] = 0.0f; t[r][c] = 0.0f; }

  // W stream: software pipeline, prefetch distance = 1 ic iteration.
  const float4* wp0 = Wv + (size_t)(o0 + 0) * IN4 + il;
  const float4* wp1 = Wv + (size_t)(o0 + 1) * IN4 + il;
  float4 wcur0 = wp0[0];
  float4 wcur1 = wp1[0];

#pragma unroll 2
  for (int ic = 0; ic < NIT; ++ic) {
    const int icn = (ic + 1 < NIT) ? (ic + 1) : (NIT - 1);
    const float4 wnxt0 = wp0[icn * 16];
    const float4 wnxt1 = wp1[icn * 16];

    float hc[BB][4];
#pragma unroll
    for (int r = 0; r < BB; ++r) {
      const float4 v = lds_h[r * IN4 + ic * 16 + il];
      hc[r][0] = v.x; hc[r][1] = v.y; hc[r][2] = v.z; hc[r][3] = v.w;
    }

    // cw = c2 * leaky_clamp(w): med3 clamp + folded-constant fma,
    // built once per ic, reused across BB rows.
    float cw[OBB][4];
    {
      const float wj0[4] = {wcur0.x, wcur0.y, wcur0.z, wcur0.w};
      const float wj1[4] = {wcur1.x, wcur1.y, wcur1.z, wcur1.w};
#pragma unroll
      for (int j = 0; j < 4; ++j) {
        float m  = fminf(fmaxf(wj0[j], 0.0f), 1.0f);      // v_med3
        cw[0][j] = fmaf(wj0[j], c01, m * c09);
        m        = fminf(fmaxf(wj1[j], 0.0f), 1.0f);
        cw[1][j] = fmaf(wj1[j], c01, m * c09);
      }
    }

    // All-trans inner loop: per z = 1 mul + 1 v_exp (trans pipe) +
    // 1 add + 1 fma. BB*OBB*4 = up to 32 independent exps per ic give
    // the scheduler plenty to interleave across both pipes.
#pragma unroll
    for (int r = 0; r < BB; ++r)
#pragma unroll
      for (int c = 0; c < OBB; ++c)
#pragma unroll
        for (int j = 0; j < 4; ++j) {
          const float arg = cw[c][j] * hc[r][j];
          const float e = EXP2F(arg);
          s[r][c] += e;
          t[r][c]  = fmaf(arg, e, t[r][c]);
        }

    wcur0 = wnxt0;
    wcur1 = wnxt1;
  }

  // Reduce partials across the 16 i-lanes of each group.
#pragma unroll
  for (int m = 1; m < 16; m <<= 1)
#pragma unroll
    for (int r = 0; r < BB; ++r)
#pragma unroll
      for (int c = 0; c < OBB; ++c) {
        s[r][c] += __shfl_xor(s[r][c], m, 64);
        t[r][c] += __shfl_xor(t[r][c], m, 64);
      }

  if (il == 0) {
    const float inv_c2 = 1.0f / c2;
#pragma unroll
    for (int r = 0; r < BB; ++r)
#pragma unroll
      for (int c = 0; c < OBB; ++c) {
        const float out = t[r][c] / s[r][c] * inv_c2;  // sum(z e)/sum(e)
        hout[(b0 + r) * OUT + (o0 + c)] = 1.0f - out;
      }
  }
}

extern "C" void kernel_launch(void* const* d_in, const int* in_sizes, int n_in,
                              void* d_out, int out_size, void* d_ws, size_t ws_size,
                              hipStream_t stream) {
  // setup_inputs() dict order: x, W0, tau0, W1, tau1, W2, tau2, W3, tau3
  const float* x    = (const float*)d_in[0];
  const float* W0   = (const float*)d_in[1];
  const float* tau0 = (const float*)d_in[2];
  const float* W1   = (const float*)d_in[3];
  const float* tau1 = (const float*)d_in[4];
  const float* W2   = (const float*)d_in[5];
  const float* tau2 = (const float*)d_in[6];
  const float* W3   = (const float*)d_in[7];
  const float* tau3 = (const float*)d_in[8];

  float* h1  = (float*)d_ws;        // 128*1024 floats
  float* h2  = h1 + 128 * 1024;     // 128*512
  float* h3  = h2 + 128 * 512;      // 128*256
  float* out = (float*)d_out;       // 128*128

  const double LOGR = 2.9444389791664403;  // log(0.95) - log(0.05) = log(19)
  const float tf1024 = (float)(log(1023.0) + LOGR);
  const float tf512  = (float)(log(511.0)  + LOGR);
  const float tf256  = (float)(log(255.0)  + LOGR);

  // Grid = (OUT/32) * (128/BB) — the validated 123.8-us configuration.
  or_layer<1024, 1024, 4, true ><<<1024, 256, 0, stream>>>(x,  W0, tau0, h1,  tf1024);
  or_layer<1024,  512, 2, false><<<1024, 256, 0, stream>>>(h1, W1, tau1, h2,  tf1024);
  or_layer< 512,  256, 1, false><<<1024, 256, 0, stream>>>(h2, W2, tau2, h3,  tf512);
  or_layer< 256,  128, 1, false><<< 512, 256, 0, stream>>>(h3, W3, tau3, out, tf256);
}